// Round 14
// baseline (393.139 us; speedup 1.0000x reference)
//
#include <hip/hip_runtime.h>
#include <hip/hip_bf16.h>

#define NUSERS 100000
#define NITEMS 50000
#define NN 150000            // total nodes
#define DD 64                // hidden dim
#define DE 16                // eigs dim
#define NE 1500000           // edges per layer
#define NPATH 14
#define LN_EPS 1e-5f

#define BROWS 1024           // rows per bucket
#define NBUK 147             // buckets per layer = ceil(NN/1024)
#define NB (2 * NBUK)        // both layers = 294
#define CHUNK 4096           // edges per pscatter block
#define NCHUNK ((NE + CHUNK - 1) / CHUNK)        // 367
#define CAP 11776            // padded slots per bucket (4 x QCAP)
#define QSPLIT 4             // bscatter blocks per bucket
#define QROWS (BROWS / QSPLIT)                   // 256 rows per quarter
#define QCAP (CAP / QSPLIT)                      // 2944 csv slots per quarter

#define EIGBLK ((NN * DE) / 256)                 // 9375 exactly

typedef float vf2 __attribute__((ext_vector_type(2)));

__device__ __forceinline__ vf2 unpk(unsigned u) {
    vf2 r;
    r.x = __uint_as_float(u << 16);
    r.y = __uint_as_float(u & 0xffff0000u);
    return r;
}
// f32 -> bf16 bits, round-to-nearest-even
__device__ __forceinline__ unsigned f2b(float f) {
    union { float f; unsigned u; } v; v.f = f;
    return (v.u + 0x7fffu + ((v.u >> 16) & 1u)) >> 16;
}

// DPP lane-permute add helper: returns value from permuted lane.
// 0xB1 = quad_perm [1,0,3,2] (xor1), 0x4E = quad_perm [2,3,0,1] (xor2),
// 0x141 = ROW_HALF_MIRROR (pairs lower4<->upper4 within each 8),
// 0x128 = ROW_ROR:8 (xor8 within each 16-lane row).
template<int CTRL>
__device__ __forceinline__ float dppmov(float x) {
    return __int_as_float(
        __builtin_amdgcn_mov_dpp(__float_as_int(x), CTRL, 0xF, 0xF, true));
}

// wave-level inclusive scan (int), no barriers
__device__ __forceinline__ int wscan(int v, int lane) {
    #pragma unroll
    for (int d = 1; d < 64; d <<= 1) {
        int u = __shfl_up(v, d, 64);
        v += (lane >= d) ? u : 0;
    }
    return v;
}

// ------- init per-bucket reservation cursors --------------------------
__global__ void k_init(int* __restrict__ curbuk) {
    int t = blockIdx.x * 256 + threadIdx.x;
    if (t < NB) curbuk[t] = t * CAP;
}

// ------- fused eigs->bf16 + layer-0 LN (no LDS, no barriers) ----------
__global__ void k_eigln(const float* __restrict__ uemb,
                        const float* __restrict__ iemb,
                        const float* __restrict__ eigs,
                        unsigned short* __restrict__ e16,
                        unsigned short* __restrict__ y) {
    int blk = blockIdx.x;
    int t = threadIdx.x;
    if (blk < EIGBLK) {
        int i = blk * 256 + t;
        e16[i] = (unsigned short)f2b(eigs[i]);
    } else {
        int row = (blk - EIGBLK) * 4 + (t >> 6);
        int lane = t & 63;
        if (row >= NN) return;
        int i = row * DD + lane;
        float v = (row < NUSERS) ? uemb[i] : iemb[i - NUSERS * DD];
        float s = v;
        #pragma unroll
        for (int m = 32; m; m >>= 1) s += __shfl_xor(s, m, 64);
        float mu = s * (1.0f / 64.0f);
        float d = v - mu;
        float q = d * d;
        #pragma unroll
        for (int m = 32; m; m >>= 1) q += __shfl_xor(q, m, 64);
        float rs = rsqrtf(q * (1.0f / 64.0f) + LN_EPS);
        y[i] = (unsigned short)f2b(d * rs);
    }
}

// ------- scatter with atomic bucket reservation -----------------------
// record = col | pt<<18 | row_local<<22   (18+4+10 = 32 bits exactly)
__global__ __launch_bounds__(512) void k_pscatter(
        const int* __restrict__ idx,
        const int* __restrict__ ptyp,
        int* __restrict__ curbuk,
        unsigned int* __restrict__ stage) {
    int blk = blockIdx.x;                 // 0 .. 2*NCHUNK-1
    int layer = blk / NCHUNK;
    int k = blk - layer * NCHUNK;
    __shared__ int h[NBUK];
    __shared__ int hofs[NBUK];
    for (int t = threadIdx.x; t < NBUK; t += 512) h[t] = 0;
    __syncthreads();
    const int* rrow = idx + (size_t)layer * 2 * NE;
    const int* ccol = rrow + NE;
    const int* pp   = ptyp + (size_t)layer * NE;
    int base = k * CHUNK;
    int lim = min(CHUNK, NE - base);
    for (int j = threadIdx.x; j < lim; j += 512)
        atomicAdd(&h[rrow[base + j] >> 10], 1);
    __syncthreads();
    for (int t = threadIdx.x; t < NBUK; t += 512) {
        int c = h[t];
        hofs[t] = c ? atomicAdd(&curbuk[layer * NBUK + t], c) : 0;
    }
    __syncthreads();
    for (int j = threadIdx.x; j < lim; j += 512) {
        int e = base + j;
        int r = rrow[e];
        int pos = atomicAdd(&hofs[r >> 10], 1);
        stage[pos] = (unsigned)ccol[e] | ((unsigned)pp[e] << 18)
                   | ((unsigned)(r & 1023) << 22);
    }
}

// ------- bucket scatter: 4 blocks per bucket ("quarters") -------------
// Each quarter-block scans the full bucket's stage records (bucket ~46KB,
// L2-resident -> cheap re-reads) but hist/scatters only its own 256-row
// range into a private padded csv sub-region [start + qq*QCAP, +QCAP).
// 1176 blocks x 512 thr (4.6 blocks/CU) vs the old 294 x 1024 (1.15/CU,
// latency-exposed). roff stays absolute, so k_row is unchanged.
__global__ __launch_bounds__(512) void k_bscatter(
        const unsigned int* __restrict__ stage,
        const int* __restrict__ curbuk,
        int* __restrict__ csv,
        int2* __restrict__ roff) {
    __shared__ int scnt[QROWS];
    __shared__ int scur[QROWS];
    __shared__ int wsum[8];
    int blk = blockIdx.x;                 // 0 .. NB*QSPLIT-1
    int b = blk >> 2;                     // bucket
    int qq = blk & 3;                     // quarter
    int t = threadIdx.x;
    int lane = t & 63, w = t >> 6;
    int layer = b / NBUK;
    int brow0 = (b - layer * NBUK) * BROWS + qq * QROWS;
    int nrows = min(QROWS, NN - brow0);   // may be <=0 for tail quarters
    int start = b * CAP;
    int n = curbuk[b] - start;
    int rlo = qq * QROWS;
    if (t < QROWS) scnt[t] = 0;
    __syncthreads();
    for (int p = t; p < n; p += 512) {
        int rl = (int)(stage[start + p] >> 22) - rlo;
        if ((unsigned)rl < QROWS) atomicAdd(&scnt[rl], 1);
    }
    __syncthreads();
    int orig = (t < QROWS) ? scnt[t] : 0;
    int s = wscan(orig, lane);            // inclusive within wave
    if (lane == 63) wsum[w] = s;
    __syncthreads();
    if (w == 0) {
        int x = (lane < 8) ? wsum[lane] : 0;
        #pragma unroll
        for (int d = 1; d < 8; d <<= 1) {
            int u = __shfl_up(x, d, 64);
            x += (lane >= d) ? u : 0;
        }
        if (lane < 8) wsum[lane] = x;
    }
    __syncthreads();
    int wb = (w > 0) ? wsum[w - 1] : 0;
    int excl = wb + s - orig;             // exclusive prefix within quarter
    int qstart = start + qq * QCAP;       // this quarter's csv region
    if (t < QROWS) {
        scur[t] = excl;
        if (t < nrows)
            roff[(size_t)layer * NN + brow0 + t] =
                make_int2(qstart + excl, qstart + excl + orig);
    }
    __syncthreads();
    for (int p = t; p < n; p += 512) {
        unsigned rec = stage[start + p];
        int rl = (int)(rec >> 22) - rlo;
        if ((unsigned)rl < QROWS) {
            int pos = atomicAdd(&scur[rl], 1);
            csv[qstart + pos] = (int)(rec & 0x3fffffu);
        }
    }
}

// ---- fused per-row: scores + dual softmax + SpMM + fused epilogue ----
// 8 edge slots x 8 dim lanes + DPP reduces + full/tail loop split.
// (byte-identical to round 13)
__global__ void k_row(const unsigned short* __restrict__ y,
                      const unsigned short* __restrict__ e16,
                      const int2* __restrict__ roff,
                      const int* __restrict__ csv,
                      const float* __restrict__ pw,   // [L, NPATH]
                      const float* __restrict__ lam,  // [L]
                      int layer,
                      const float* __restrict__ uemb,
                      const float* __restrict__ iemb,
                      float* __restrict__ x1,
                      unsigned short* __restrict__ y1,
                      float* __restrict__ out) {
    __shared__ float pexp[NPATH];
    __shared__ float selam;
    int t = threadIdx.x;
    if (t < NPATH) pexp[t] = fminf(expf(pw[layer * NPATH + t]), 5.0f);
    if (t == NPATH) selam = expf(lam[layer]);
    __syncthreads();

    int row = blockIdx.x * 4 + (t >> 6);     // NN % 4 == 0
    int lane = t & 63;
    int g = lane >> 3;                        // edge slot 0..7
    int sl = lane & 7;                        // dim group: dims 8sl..8sl+7
    int2 pr = roff[row];
    int p0 = pr.x, p1 = pr.y;

    uint4 ar = reinterpret_cast<const uint4*>(y + (size_t)row * DD)[sl];
    vf2 a0 = unpk(ar.x), a1 = unpk(ar.y), a2 = unpk(ar.z), a3 = unpk(ar.w);
    unsigned eru = reinterpret_cast<const unsigned*>(e16 + (size_t)row * DE)[sl];
    vf2 er = unpk(eru);
    float elam = selam;

    float sum0 = 0.f, sum1 = 0.f;
    vf2 A0 = {0.f, 0.f}, A1 = {0.f, 0.f}, A2 = {0.f, 0.f}, A3 = {0.f, 0.f};
    vf2 B0 = {0.f, 0.f}, B1 = {0.f, 0.f}, B2 = {0.f, 0.f}, B3 = {0.f, 0.f};

    int pend = p0 + ((p1 - p0) & ~7);         // full-trip boundary

    for (int p = p0; p < pend; p += 8) {      // full trips: no bounds logic
        int rec = csv[p + g];
        int c = rec & 0x3ffff;
        uint4 bv = reinterpret_cast<const uint4*>(y + (size_t)c * DD)[sl];
        unsigned ecu = reinterpret_cast<const unsigned*>(e16 + (size_t)c * DE)[sl];
        vf2 b0 = unpk(bv.x), b1 = unpk(bv.y), b2 = unpk(bv.z), b3 = unpk(bv.w);
        vf2 px = a0 * b0;
        px += a1 * b1;
        px += a2 * b2;
        px += a3 * b3;
        vf2 ec = unpk(ecu);
        vf2 tt = px * 0.125f + (er * ec) * elam;
        float sc = tt.x + tt.y;
        sc += dppmov<0xB1>(sc);               // xor1
        sc += dppmov<0x4E>(sc);               // xor2
        sc += dppmov<0x141>(sc);              // 4<->4 combine
        float e0 = fminf(__expf(sc), 5.0f);
        float e1 = pexp[(rec >> 18) & 0xF];
        sum0 += e0; sum1 += e1;
        A0 += e0 * b0; A1 += e0 * b1; A2 += e0 * b2; A3 += e0 * b3;
        B0 += e1 * b0; B1 += e1 * b1; B2 += e1 * b2; B3 += e1 * b3;
    }

    if (pend < p1) {                          // tail trip: guarded
        int q = pend + g;
        int qc = (q < p1) ? q : (p1 - 1);     // always-valid gather index
        int rec = csv[qc];
        int c = rec & 0x3ffff;
        uint4 bv = reinterpret_cast<const uint4*>(y + (size_t)c * DD)[sl];
        unsigned ecu = reinterpret_cast<const unsigned*>(e16 + (size_t)c * DE)[sl];
        vf2 b0 = unpk(bv.x), b1 = unpk(bv.y), b2 = unpk(bv.z), b3 = unpk(bv.w);
        vf2 px = a0 * b0;
        px += a1 * b1;
        px += a2 * b2;
        px += a3 * b3;
        vf2 ec = unpk(ecu);
        vf2 tt = px * 0.125f + (er * ec) * elam;
        float sc = tt.x + tt.y;
        sc += dppmov<0xB1>(sc);
        sc += dppmov<0x4E>(sc);
        sc += dppmov<0x141>(sc);
        bool ok = q < p1;
        float e0 = ok ? fminf(__expf(sc), 5.0f) : 0.f;
        float e1 = ok ? pexp[(rec >> 18) & 0xF] : 0.f;
        sum0 += e0; sum1 += e1;
        A0 += e0 * b0; A1 += e0 * b1; A2 += e0 * b2; A3 += e0 * b3;
        B0 += e1 * b0; B1 += e1 * b1; B2 += e1 * b2; B3 += e1 * b3;
    }

    // reduce over the 8 edge groups: xor8 via DPP row_ror:8, rest via shfl
    sum0 += dppmov<0x128>(sum0);
    sum1 += dppmov<0x128>(sum1);
    #pragma unroll
    for (int m = 16; m <= 32; m <<= 1) {
        sum0 += __shfl_xor(sum0, m, 64);
        sum1 += __shfl_xor(sum1, m, 64);
    }
    float rinv0 = 0.5f / ((sum0 == 0.f) ? 1.f : sum0);
    float rinv1 = 0.5f / ((sum1 == 0.f) ? 1.f : sum1);

    vf2 o0 = rinv0 * A0 + rinv1 * B0, o1 = rinv0 * A1 + rinv1 * B1;
    vf2 o2 = rinv0 * A2 + rinv1 * B2, o3 = rinv0 * A3 + rinv1 * B3;
    o0.x += dppmov<0x128>(o0.x); o0.y += dppmov<0x128>(o0.y);
    o1.x += dppmov<0x128>(o1.x); o1.y += dppmov<0x128>(o1.y);
    o2.x += dppmov<0x128>(o2.x); o2.y += dppmov<0x128>(o2.y);
    o3.x += dppmov<0x128>(o3.x); o3.y += dppmov<0x128>(o3.y);
    #pragma unroll
    for (int m = 16; m <= 32; m <<= 1) {
        vf2 s;
        s.x = __shfl_xor(o0.x, m, 64); s.y = __shfl_xor(o0.y, m, 64); o0 += s;
        s.x = __shfl_xor(o1.x, m, 64); s.y = __shfl_xor(o1.y, m, 64); o1 += s;
        s.x = __shfl_xor(o2.x, m, 64); s.y = __shfl_xor(o2.y, m, 64); o2 += s;
        s.x = __shfl_xor(o3.x, m, 64); s.y = __shfl_xor(o3.y, m, 64); o3 += s;
    }
    if (g == 0) {
        int ofs = sl * 8;
        float v0 = o0.x, v1 = o0.y, v2 = o1.x, v3 = o1.y;
        float v4 = o2.x, v5 = o2.y, v6 = o3.x, v7 = o3.y;
        if (layer == 0) {
            float* dst = x1 + (size_t)row * DD + ofs;
            reinterpret_cast<float4*>(dst)[0] = make_float4(v0, v1, v2, v3);
            reinterpret_cast<float4*>(dst)[1] = make_float4(v4, v5, v6, v7);
            // LN of x1 row across 8 lanes x 8 vals -> y1 (bf16)
            float s = v0+v1+v2+v3+v4+v5+v6+v7;
            s += __shfl_xor(s, 1, 64);
            s += __shfl_xor(s, 2, 64);
            s += __shfl_xor(s, 4, 64);
            float mu = s * (1.0f / 64.0f);
            float d0=v0-mu, d1=v1-mu, d2=v2-mu, d3=v3-mu;
            float d4=v4-mu, d5=v5-mu, d6=v6-mu, d7=v7-mu;
            float qv = d0*d0+d1*d1+d2*d2+d3*d3+d4*d4+d5*d5+d6*d6+d7*d7;
            qv += __shfl_xor(qv, 1, 64);
            qv += __shfl_xor(qv, 2, 64);
            qv += __shfl_xor(qv, 4, 64);
            float rs = rsqrtf(qv * (1.0f / 64.0f) + LN_EPS);
            uint4 pk;
            pk.x = f2b(d0*rs) | (f2b(d1*rs) << 16);
            pk.y = f2b(d2*rs) | (f2b(d3*rs) << 16);
            pk.z = f2b(d4*rs) | (f2b(d5*rs) << 16);
            pk.w = f2b(d6*rs) | (f2b(d7*rs) << 16);
            reinterpret_cast<uint4*>(y1 + (size_t)row * DD)[sl] = pk;
        } else {
            const float* e = (row < NUSERS)
                ? (uemb + (size_t)row * DD + ofs)
                : (iemb + (size_t)(row - NUSERS) * DD + ofs);
            const float* xp = x1 + (size_t)row * DD + ofs;
            float4 ea = reinterpret_cast<const float4*>(e)[0];
            float4 eb = reinterpret_cast<const float4*>(e)[1];
            float4 xa = reinterpret_cast<const float4*>(xp)[0];
            float4 xb = reinterpret_cast<const float4*>(xp)[1];
            float* dst = out + (size_t)row * DD + ofs;
            const float k3 = 1.0f / 3.0f;
            reinterpret_cast<float4*>(dst)[0] = make_float4(
                (ea.x + xa.x + v0) * k3, (ea.y + xa.y + v1) * k3,
                (ea.z + xa.z + v2) * k3, (ea.w + xa.w + v3) * k3);
            reinterpret_cast<float4*>(dst)[1] = make_float4(
                (eb.x + xb.x + v4) * k3, (eb.y + xb.y + v5) * k3,
                (eb.z + xb.z + v6) * k3, (eb.w + xb.w + v7) * k3);
        }
    }
}

extern "C" void kernel_launch(void* const* d_in, const int* in_sizes, int n_in,
                              void* d_out, int out_size, void* d_ws, size_t ws_size,
                              hipStream_t stream) {
    const float* uemb = (const float*)d_in[0];
    const float* iemb = (const float*)d_in[1];
    const float* eigs = (const float*)d_in[2];
    const float* lam  = (const float*)d_in[3];
    const float* pw   = (const float*)d_in[4];
    const int* idx    = (const int*)d_in[5];   // [L, 2, E]
    const int* ptyp   = (const int*)d_in[6];   // [L, E]

    char* w = (char*)d_ws;
    // stage aliases x1's region: stage's lifetime (pscatter->bscatter)
    // ends before x1 is first written (layer-0 k_row).
    unsigned int*   stage  = (unsigned int*)(w);               // 13,848,576
    float*          x1     = (float*)(w);                      // 38,400,000
    unsigned short* y0     = (unsigned short*)(w + 38400000);  // 19,200,000
    unsigned short* y1     = (unsigned short*)(w + 57600000);  // 19,200,000
    int*            csv    = (int*)(w + 76800000);             // 13,848,576
    int2*           roff   = (int2*)(w + 90648576);            //  2,400,000
    unsigned short* e16    = (unsigned short*)(w + 93048576);  //  4,800,000
    int*            curbuk = (int*)(w + 97848576);             //      1,176
    // total ~97.85 MB

    // CSR build: reserve + scatter + quarter-parallel bucket sort
    k_init<<<2, 256, 0, stream>>>(curbuk);
    k_pscatter<<<2 * NCHUNK, 512, 0, stream>>>(idx, ptyp, curbuk, stage);
    k_bscatter<<<NB * QSPLIT, 512, 0, stream>>>(stage, curbuk, csv, roff);

    // fused eigs->bf16 + layer-0 LN
    const int gRows = NN / 4;                    // 37,500
    k_eigln<<<EIGBLK + gRows, 256, 0, stream>>>(uemb, iemb, eigs, e16, y0);

    // layer 0: writes x1 + y1=LN(x1)
    k_row<<<gRows, 256, 0, stream>>>(y0, e16, roff, csv, pw, lam, 0,
                                     nullptr, nullptr, x1, y1, nullptr);
    // layer 1: writes final output (emb + x1 + x2)/3
    k_row<<<gRows, 256, 0, stream>>>(y1, e16, roff + NN, csv, pw, lam, 1,
                                     uemb, iemb, x1, nullptr, (float*)d_out);
}

// Round 16
// 376.421 us; speedup vs baseline: 1.0444x; 1.0444x over previous
//
#include <hip/hip_runtime.h>
#include <hip/hip_bf16.h>

#define NUSERS 100000
#define NITEMS 50000
#define NN 150000            // total nodes
#define DD 64                // hidden dim
#define DE 16                // eigs dim
#define NE 1500000           // edges per layer
#define NPATH 14
#define LN_EPS 1e-5f

#define BROWS 1024           // rows per bucket
#define NBUK 147             // buckets per layer = ceil(NN/1024)
#define NB (2 * NBUK)        // both layers = 294
#define CHUNK 4096           // edges per pscatter block
#define NCHUNK ((NE + CHUNK - 1) / CHUNK)        // 367
#define CAP 11776            // padded slots per bucket (mean 10204, +10 sigma)

#define PSB (2 * NCHUNK)                         // 734 pscatter blocks
#define EGB ((NN * DE + 511) / 512)              // 4688 eig blocks
#define LNB (NN / 8)                             // 18750 LN blocks (512 thr)

typedef float vf2 __attribute__((ext_vector_type(2)));

__device__ __forceinline__ vf2 unpk(unsigned u) {
    vf2 r;
    r.x = __uint_as_float(u << 16);
    r.y = __uint_as_float(u & 0xffff0000u);
    return r;
}
// f32 -> bf16 bits, round-to-nearest-even
__device__ __forceinline__ unsigned f2b(float f) {
    union { float f; unsigned u; } v; v.f = f;
    return (v.u + 0x7fffu + ((v.u >> 16) & 1u)) >> 16;
}

// DPP lane-permute add helper: returns value from permuted lane.
// 0xB1 = quad_perm [1,0,3,2] (xor1), 0x4E = quad_perm [2,3,0,1] (xor2),
// 0x141 = ROW_HALF_MIRROR (pairs lower4<->upper4 within each 8),
// 0x128 = ROW_ROR:8 (xor8 within each 16-lane row).
template<int CTRL>
__device__ __forceinline__ float dppmov(float x) {
    return __int_as_float(
        __builtin_amdgcn_mov_dpp(__float_as_int(x), CTRL, 0xF, 0xF, true));
}

// wave-level inclusive scan (int), no barriers
__device__ __forceinline__ int wscan(int v, int lane) {
    #pragma unroll
    for (int d = 1; d < 64; d <<= 1) {
        int u = __shfl_up(v, d, 64);
        v += (lane >= d) ? u : 0;
    }
    return v;
}

// ------- fused: pscatter | eigs->bf16 | layer-0 LN --------------------
// blocks [0, PSB)          : edge scatter with atomic bucket reservation
// blocks [PSB, PSB+EGB)    : eigs f32 -> bf16
// blocks [.., +LNB)        : LN(emb) -> y0 bf16 (8 rows per 512-thr block)
// All three are independent; fusing lets the BW-bound eig/LN blocks fill
// the CUs that the latency-bound pscatter blocks leave idle (same-stream
// kernels serialize, so separate launches can never overlap).
// record = col | pt<<18 | row_local<<22   (18+4+10 = 32 bits exactly)
__global__ __launch_bounds__(512) void k_psc_eig(
        const float* __restrict__ uemb,
        const float* __restrict__ iemb,
        const float* __restrict__ eigs,
        const int* __restrict__ idx,
        const int* __restrict__ ptyp,
        int* __restrict__ curbuk,         // [NB], pre-zeroed (relative)
        unsigned int* __restrict__ stage,
        unsigned short* __restrict__ e16,
        unsigned short* __restrict__ y) {
    int blk = blockIdx.x;
    int t = threadIdx.x;
    if (blk < PSB) {
        int layer = blk / NCHUNK;
        int k = blk - layer * NCHUNK;
        __shared__ int h[NBUK];
        __shared__ int hofs[NBUK];
        for (int j = t; j < NBUK; j += 512) h[j] = 0;
        __syncthreads();
        const int* rrow = idx + (size_t)layer * 2 * NE;
        const int* ccol = rrow + NE;
        const int* pp   = ptyp + (size_t)layer * NE;
        int base = k * CHUNK;
        int lim = min(CHUNK, NE - base);
        for (int j = t; j < lim; j += 512)
            atomicAdd(&h[rrow[base + j] >> 10], 1);
        __syncthreads();
        for (int j = t; j < NBUK; j += 512) {
            int c = h[j];
            int gb = layer * NBUK + j;
            hofs[j] = c ? (gb * CAP + atomicAdd(&curbuk[gb], c)) : 0;
        }
        __syncthreads();
        for (int j = t; j < lim; j += 512) {
            int e = base + j;
            int r = rrow[e];
            int pos = atomicAdd(&hofs[r >> 10], 1);
            stage[pos] = (unsigned)ccol[e] | ((unsigned)pp[e] << 18)
                       | ((unsigned)(r & 1023) << 22);
        }
    } else if (blk < PSB + EGB) {
        int i = (blk - PSB) * 512 + t;
        if (i < NN * DE) e16[i] = (unsigned short)f2b(eigs[i]);
    } else {
        int row = (blk - PSB - EGB) * 8 + (t >> 6);   // NN % 8 == 0
        int lane = t & 63;
        int i = row * DD + lane;
        float v = (row < NUSERS) ? uemb[i] : iemb[i - NUSERS * DD];
        float s = v;
        #pragma unroll
        for (int m = 32; m; m >>= 1) s += __shfl_xor(s, m, 64);
        float mu = s * (1.0f / 64.0f);
        float d = v - mu;
        float q = d * d;
        #pragma unroll
        for (int m = 32; m; m >>= 1) q += __shfl_xor(q, m, 64);
        float rs = rsqrtf(q * (1.0f / 64.0f) + LN_EPS);
        y[i] = (unsigned short)f2b(d * rs);
    }
}

// ------- bucket scatter: LDS hist + wave-scan -> roff + csv -----------
// Round-13 structure (294 blocks x 1024 thr) + register-cached records:
// each thread keeps its <=12 stage records in compile-time-indexed VGPRs
// so phase 2 re-reads nothing from global.
__global__ __launch_bounds__(1024) void k_bscatter(
        const unsigned int* __restrict__ stage,
        const int* __restrict__ curbuk,
        int* __restrict__ csv,
        int2* __restrict__ roff) {
    __shared__ int scnt[BROWS];
    __shared__ int scur[BROWS];
    __shared__ int wsum[16];
    int b = blockIdx.x;
    int t = threadIdx.x;
    int lane = t & 63, w = t >> 6;
    int layer = b / NBUK;
    int brow0 = (b - layer * NBUK) * BROWS;
    int nrows = min(BROWS, NN - brow0);
    int start = b * CAP;
    int n = min(curbuk[b], CAP);          // relative count
    unsigned recs[12];                    // CAP/1024 = 11.5 -> 12 max
    #pragma unroll
    for (int i = 0; i < 12; ++i) {
        int p = t + i * 1024;
        recs[i] = (p < n) ? stage[start + p] : 0u;
    }
    scnt[t] = 0;
    __syncthreads();
    #pragma unroll
    for (int i = 0; i < 12; ++i) {
        int p = t + i * 1024;
        if (p < n) atomicAdd(&scnt[recs[i] >> 22], 1);
    }
    __syncthreads();
    int orig = scnt[t];
    int s = wscan(orig, lane);            // inclusive within wave
    if (lane == 63) wsum[w] = s;
    __syncthreads();
    if (w == 0) {
        int x = (lane < 16) ? wsum[lane] : 0;
        #pragma unroll
        for (int d = 1; d < 16; d <<= 1) {
            int u = __shfl_up(x, d, 64);
            x += (lane >= d) ? u : 0;
        }
        if (lane < 16) wsum[lane] = x;
    }
    __syncthreads();
    int wb = (w > 0) ? wsum[w - 1] : 0;
    int excl = wb + s - orig;             // exclusive prefix
    scur[t] = excl;
    if (t < nrows)
        roff[(size_t)layer * NN + brow0 + t] =
            make_int2(start + excl, start + excl + orig);
    __syncthreads();
    #pragma unroll
    for (int i = 0; i < 12; ++i) {
        int p = t + i * 1024;
        if (p < n) {
            unsigned rec = recs[i];
            int pos = atomicAdd(&scur[rec >> 22], 1);
            csv[start + pos] = (int)(rec & 0x3fffffu);
        }
    }
}

// ---- fused per-row: scores + dual softmax + SpMM + fused epilogue ----
// 8 edge slots x 8 dim lanes + DPP reduces + full/tail loop split.
// (byte-identical to round 13)
__global__ void k_row(const unsigned short* __restrict__ y,
                      const unsigned short* __restrict__ e16,
                      const int2* __restrict__ roff,
                      const int* __restrict__ csv,
                      const float* __restrict__ pw,   // [L, NPATH]
                      const float* __restrict__ lam,  // [L]
                      int layer,
                      const float* __restrict__ uemb,
                      const float* __restrict__ iemb,
                      float* __restrict__ x1,
                      unsigned short* __restrict__ y1,
                      float* __restrict__ out) {
    __shared__ float pexp[NPATH];
    __shared__ float selam;
    int t = threadIdx.x;
    if (t < NPATH) pexp[t] = fminf(expf(pw[layer * NPATH + t]), 5.0f);
    if (t == NPATH) selam = expf(lam[layer]);
    __syncthreads();

    int row = blockIdx.x * 4 + (t >> 6);     // NN % 4 == 0
    int lane = t & 63;
    int g = lane >> 3;                        // edge slot 0..7
    int sl = lane & 7;                        // dim group: dims 8sl..8sl+7
    int2 pr = roff[row];
    int p0 = pr.x, p1 = pr.y;

    uint4 ar = reinterpret_cast<const uint4*>(y + (size_t)row * DD)[sl];
    vf2 a0 = unpk(ar.x), a1 = unpk(ar.y), a2 = unpk(ar.z), a3 = unpk(ar.w);
    unsigned eru = reinterpret_cast<const unsigned*>(e16 + (size_t)row * DE)[sl];
    vf2 er = unpk(eru);
    float elam = selam;

    float sum0 = 0.f, sum1 = 0.f;
    vf2 A0 = {0.f, 0.f}, A1 = {0.f, 0.f}, A2 = {0.f, 0.f}, A3 = {0.f, 0.f};
    vf2 B0 = {0.f, 0.f}, B1 = {0.f, 0.f}, B2 = {0.f, 0.f}, B3 = {0.f, 0.f};

    int pend = p0 + ((p1 - p0) & ~7);         // full-trip boundary

    for (int p = p0; p < pend; p += 8) {      // full trips: no bounds logic
        int rec = csv[p + g];
        int c = rec & 0x3ffff;
        uint4 bv = reinterpret_cast<const uint4*>(y + (size_t)c * DD)[sl];
        unsigned ecu = reinterpret_cast<const unsigned*>(e16 + (size_t)c * DE)[sl];
        vf2 b0 = unpk(bv.x), b1 = unpk(bv.y), b2 = unpk(bv.z), b3 = unpk(bv.w);
        vf2 px = a0 * b0;
        px += a1 * b1;
        px += a2 * b2;
        px += a3 * b3;
        vf2 ec = unpk(ecu);
        vf2 tt = px * 0.125f + (er * ec) * elam;
        float sc = tt.x + tt.y;
        sc += dppmov<0xB1>(sc);               // xor1
        sc += dppmov<0x4E>(sc);               // xor2
        sc += dppmov<0x141>(sc);              // 4<->4 combine
        float e0 = fminf(__expf(sc), 5.0f);
        float e1 = pexp[(rec >> 18) & 0xF];
        sum0 += e0; sum1 += e1;
        A0 += e0 * b0; A1 += e0 * b1; A2 += e0 * b2; A3 += e0 * b3;
        B0 += e1 * b0; B1 += e1 * b1; B2 += e1 * b2; B3 += e1 * b3;
    }

    if (pend < p1) {                          // tail trip: guarded
        int q = pend + g;
        int qc = (q < p1) ? q : (p1 - 1);     // always-valid gather index
        int rec = csv[qc];
        int c = rec & 0x3ffff;
        uint4 bv = reinterpret_cast<const uint4*>(y + (size_t)c * DD)[sl];
        unsigned ecu = reinterpret_cast<const unsigned*>(e16 + (size_t)c * DE)[sl];
        vf2 b0 = unpk(bv.x), b1 = unpk(bv.y), b2 = unpk(bv.z), b3 = unpk(bv.w);
        vf2 px = a0 * b0;
        px += a1 * b1;
        px += a2 * b2;
        px += a3 * b3;
        vf2 ec = unpk(ecu);
        vf2 tt = px * 0.125f + (er * ec) * elam;
        float sc = tt.x + tt.y;
        sc += dppmov<0xB1>(sc);
        sc += dppmov<0x4E>(sc);
        sc += dppmov<0x141>(sc);
        bool ok = q < p1;
        float e0 = ok ? fminf(__expf(sc), 5.0f) : 0.f;
        float e1 = ok ? pexp[(rec >> 18) & 0xF] : 0.f;
        sum0 += e0; sum1 += e1;
        A0 += e0 * b0; A1 += e0 * b1; A2 += e0 * b2; A3 += e0 * b3;
        B0 += e1 * b0; B1 += e1 * b1; B2 += e1 * b2; B3 += e1 * b3;
    }

    // reduce over the 8 edge groups: xor8 via DPP row_ror:8, rest via shfl
    sum0 += dppmov<0x128>(sum0);
    sum1 += dppmov<0x128>(sum1);
    #pragma unroll
    for (int m = 16; m <= 32; m <<= 1) {
        sum0 += __shfl_xor(sum0, m, 64);
        sum1 += __shfl_xor(sum1, m, 64);
    }
    float rinv0 = 0.5f / ((sum0 == 0.f) ? 1.f : sum0);
    float rinv1 = 0.5f / ((sum1 == 0.f) ? 1.f : sum1);

    vf2 o0 = rinv0 * A0 + rinv1 * B0, o1 = rinv0 * A1 + rinv1 * B1;
    vf2 o2 = rinv0 * A2 + rinv1 * B2, o3 = rinv0 * A3 + rinv1 * B3;
    o0.x += dppmov<0x128>(o0.x); o0.y += dppmov<0x128>(o0.y);
    o1.x += dppmov<0x128>(o1.x); o1.y += dppmov<0x128>(o1.y);
    o2.x += dppmov<0x128>(o2.x); o2.y += dppmov<0x128>(o2.y);
    o3.x += dppmov<0x128>(o3.x); o3.y += dppmov<0x128>(o3.y);
    #pragma unroll
    for (int m = 16; m <= 32; m <<= 1) {
        vf2 s;
        s.x = __shfl_xor(o0.x, m, 64); s.y = __shfl_xor(o0.y, m, 64); o0 += s;
        s.x = __shfl_xor(o1.x, m, 64); s.y = __shfl_xor(o1.y, m, 64); o1 += s;
        s.x = __shfl_xor(o2.x, m, 64); s.y = __shfl_xor(o2.y, m, 64); o2 += s;
        s.x = __shfl_xor(o3.x, m, 64); s.y = __shfl_xor(o3.y, m, 64); o3 += s;
    }
    if (g == 0) {
        int ofs = sl * 8;
        float v0 = o0.x, v1 = o0.y, v2 = o1.x, v3 = o1.y;
        float v4 = o2.x, v5 = o2.y, v6 = o3.x, v7 = o3.y;
        if (layer == 0) {
            float* dst = x1 + (size_t)row * DD + ofs;
            reinterpret_cast<float4*>(dst)[0] = make_float4(v0, v1, v2, v3);
            reinterpret_cast<float4*>(dst)[1] = make_float4(v4, v5, v6, v7);
            // LN of x1 row across 8 lanes x 8 vals -> y1 (bf16)
            float s = v0+v1+v2+v3+v4+v5+v6+v7;
            s += __shfl_xor(s, 1, 64);
            s += __shfl_xor(s, 2, 64);
            s += __shfl_xor(s, 4, 64);
            float mu = s * (1.0f / 64.0f);
            float d0=v0-mu, d1=v1-mu, d2=v2-mu, d3=v3-mu;
            float d4=v4-mu, d5=v5-mu, d6=v6-mu, d7=v7-mu;
            float qv = d0*d0+d1*d1+d2*d2+d3*d3+d4*d4+d5*d5+d6*d6+d7*d7;
            qv += __shfl_xor(qv, 1, 64);
            qv += __shfl_xor(qv, 2, 64);
            qv += __shfl_xor(qv, 4, 64);
            float rs = rsqrtf(qv * (1.0f / 64.0f) + LN_EPS);
            uint4 pk;
            pk.x = f2b(d0*rs) | (f2b(d1*rs) << 16);
            pk.y = f2b(d2*rs) | (f2b(d3*rs) << 16);
            pk.z = f2b(d4*rs) | (f2b(d5*rs) << 16);
            pk.w = f2b(d6*rs) | (f2b(d7*rs) << 16);
            reinterpret_cast<uint4*>(y1 + (size_t)row * DD)[sl] = pk;
        } else {
            const float* e = (row < NUSERS)
                ? (uemb + (size_t)row * DD + ofs)
                : (iemb + (size_t)(row - NUSERS) * DD + ofs);
            const float* xp = x1 + (size_t)row * DD + ofs;
            float4 ea = reinterpret_cast<const float4*>(e)[0];
            float4 eb = reinterpret_cast<const float4*>(e)[1];
            float4 xa = reinterpret_cast<const float4*>(xp)[0];
            float4 xb = reinterpret_cast<const float4*>(xp)[1];
            float* dst = out + (size_t)row * DD + ofs;
            const float k3 = 1.0f / 3.0f;
            reinterpret_cast<float4*>(dst)[0] = make_float4(
                (ea.x + xa.x + v0) * k3, (ea.y + xa.y + v1) * k3,
                (ea.z + xa.z + v2) * k3, (ea.w + xa.w + v3) * k3);
            reinterpret_cast<float4*>(dst)[1] = make_float4(
                (eb.x + xb.x + v4) * k3, (eb.y + xb.y + v5) * k3,
                (eb.z + xb.z + v6) * k3, (eb.w + xb.w + v7) * k3);
        }
    }
}

extern "C" void kernel_launch(void* const* d_in, const int* in_sizes, int n_in,
                              void* d_out, int out_size, void* d_ws, size_t ws_size,
                              hipStream_t stream) {
    const float* uemb = (const float*)d_in[0];
    const float* iemb = (const float*)d_in[1];
    const float* eigs = (const float*)d_in[2];
    const float* lam  = (const float*)d_in[3];
    const float* pw   = (const float*)d_in[4];
    const int* idx    = (const int*)d_in[5];   // [L, 2, E]
    const int* ptyp   = (const int*)d_in[6];   // [L, E]

    char* w = (char*)d_ws;
    // stage aliases x1's region: stage's lifetime (pscatter->bscatter)
    // ends before x1 is first written (layer-0 k_row).
    unsigned int*   stage  = (unsigned int*)(w);               // 13,848,576
    float*          x1     = (float*)(w);                      // 38,400,000
    unsigned short* y0     = (unsigned short*)(w + 38400000);  // 19,200,000
    unsigned short* y1     = (unsigned short*)(w + 57600000);  // 19,200,000
    int*            csv    = (int*)(w + 76800000);             // 13,848,576
    int2*           roff   = (int2*)(w + 90648576);            //  2,400,000
    unsigned short* e16    = (unsigned short*)(w + 93048576);  //  4,800,000
    int*            curbuk = (int*)(w + 97848576);             //      1,176
    // total ~97.85 MB

    // CSR build + pre-pass: memset cursors, then ONE fused launch for
    // {edge scatter | eigs->bf16 | layer-0 LN}, then bucket sort.
    hipMemsetAsync(curbuk, 0, NB * sizeof(int), stream);
    k_psc_eig<<<PSB + EGB + LNB, 512, 0, stream>>>(
        uemb, iemb, eigs, idx, ptyp, curbuk, stage, e16, y0);
    k_bscatter<<<NB, 1024, 0, stream>>>(stage, curbuk, csv, roff);

    // layer 0: writes x1 + y1=LN(x1)
    const int gRows = NN / 4;                    // 37,500
    k_row<<<gRows, 256, 0, stream>>>(y0, e16, roff, csv, pw, lam, 0,
                                     nullptr, nullptr, x1, y1, nullptr);
    // layer 1: writes final output (emb + x1 + x2)/3
    k_row<<<gRows, 256, 0, stream>>>(y1, e16, roff + NN, csv, pw, lam, 1,
                                     uemb, iemb, x1, nullptr, (float*)d_out);
}